// Round 3
// baseline (35105.087 us; speedup 1.0000x reference)
//
#include <hip/hip_runtime.h>
#include <stdint.h>

#define T_ 512
#define B_ 64
#define IN_ 512
#define H_ 1024
#define RB 16
#define NCG 32
#define RING 8
#define LNEPS 1e-5f

typedef __attribute__((ext_vector_type(8))) short s16x8;
typedef __attribute__((ext_vector_type(4))) float f32x4;
typedef __attribute__((ext_vector_type(4))) float float4v;
typedef unsigned short ushort_t;

__device__ __forceinline__ unsigned short f2bf(float f) {
  unsigned u = __builtin_bit_cast(unsigned, f);
  return (unsigned short)((u + 0x7FFFu + ((u >> 16) & 1u)) >> 16);
}
__device__ __forceinline__ float bf2f(unsigned short h) {
  return __builtin_bit_cast(float, (unsigned)h << 16);
}
__device__ __forceinline__ float tanh_fast(float y) {
  y = fminf(15.f, fmaxf(-15.f, y));
  float t = __expf(2.f * y);
  return (t - 1.f) / (t + 1.f);
}
struct HiLo { short hi, lo; };
__device__ __forceinline__ HiLo split1(float v) {
  HiLo r;
  unsigned short h = f2bf(v);
  r.hi = (short)h;
  r.lo = (short)f2bf(v - bf2f(h));
  return r;
}
// load 8 fp32 weights -> hi/lo bf16 fragments
__device__ __forceinline__ void ldw8s(const float* p, s16x8& hi, s16x8& lo) {
  float4v a = *(const float4v*)p;
  float4v b = *(const float4v*)(p + 4);
#pragma unroll
  for (int i = 0; i < 4; ++i) {
    HiLo x = split1(a[i]); hi[i] = x.hi; lo[i] = x.lo;
    HiLo y = split1(b[i]); hi[4 + i] = y.hi; lo[4 + i] = y.lo;
  }
}
__device__ __forceinline__ void spinN(const int* p, int target) {
  int n = 0;
  while (__hip_atomic_load(p, __ATOMIC_ACQUIRE, __HIP_MEMORY_SCOPE_AGENT) < target) {
    __builtin_amdgcn_s_sleep(1);
    if (++n > 10000000) return;  // safety bound: wrong data instead of hang
  }
}
__device__ __forceinline__ void addrel(int* p) {
  __hip_atomic_fetch_add(p, 1, __ATOMIC_RELEASE, __HIP_MEMORY_SCOPE_AGENT);
}

// ---- staging helpers (all 512 threads) ----
// fp32 rows [16][1024] -> split hi/lo bf16 LDS
__device__ __forceinline__ void stageSplitF32(const float* src, ushort_t (*dh)[1032],
                                              ushort_t (*dl)[1032], int tid) {
  int r = tid >> 5, c0 = (tid & 31) * 32;
  const float* p = src + (size_t)r * H_ + c0;
#pragma unroll
  for (int q = 0; q < 4; ++q) {
    float4v a = *(const float4v*)(p + q * 8);
    float4v b = *(const float4v*)(p + q * 8 + 4);
    s16x8 hi, lo;
#pragma unroll
    for (int i = 0; i < 4; ++i) {
      HiLo x = split1(a[i]); hi[i] = x.hi; lo[i] = x.lo;
      HiLo y = split1(b[i]); hi[4 + i] = y.hi; lo[4 + i] = y.lo;
    }
    *(s16x8*)&dh[r][c0 + q * 8] = hi;
    *(s16x8*)&dl[r][c0 + q * 8] = lo;
  }
}
// x rows [16][512] fp32 -> split hi/lo LDS
__device__ __forceinline__ void stageSplitX(const float* src, ushort_t (*dh)[1032],
                                            ushort_t (*dl)[1032], int tid) {
  int r = tid >> 5, c0 = (tid & 31) * 16;
  const float* p = src + (size_t)r * IN_ + c0;
#pragma unroll
  for (int q = 0; q < 2; ++q) {
    float4v a = *(const float4v*)(p + q * 8);
    float4v b = *(const float4v*)(p + q * 8 + 4);
    s16x8 hi, lo;
#pragma unroll
    for (int i = 0; i < 4; ++i) {
      HiLo x = split1(a[i]); hi[i] = x.hi; lo[i] = x.lo;
      HiLo y = split1(b[i]); hi[4 + i] = y.hi; lo[4 + i] = y.lo;
    }
    *(s16x8*)&dh[r][c0 + q * 8] = hi;
    *(s16x8*)&dl[r][c0 + q * 8] = lo;
  }
}
// fp32 pre rows [16][1024] -> LN(ln0)+tanh -> split hi/lo LDS (or fp32 global if gdst)
// NOTE: contains internal __syncthreads
__device__ __forceinline__ void stageLTSplit(const float* src, ushort_t (*dh)[1032],
                                             ushort_t (*dl)[1032], const float* lnw,
                                             const float* lnb, float (*rstat)[2], int tid,
                                             float* gdst) {
  int r = tid >> 5, c0 = (tid & 31) * 32;
  const float* p = src + (size_t)r * H_ + c0;
  float f[32];
  float s = 0.f, ss = 0.f;
#pragma unroll
  for (int q = 0; q < 8; ++q) {
    float4v v = *(const float4v*)(p + q * 4);
#pragma unroll
    for (int i = 0; i < 4; ++i) { float x = v[i]; f[q * 4 + i] = x; s += x; ss += x * x; }
  }
#pragma unroll
  for (int m = 1; m <= 16; m <<= 1) { s += __shfl_xor(s, m, 64); ss += __shfl_xor(ss, m, 64); }
  if ((tid & 31) == 0) { rstat[r][0] = s; rstat[r][1] = ss; }
  __syncthreads();
  float mu = rstat[r][0] * (1.f / H_);
  float var = rstat[r][1] * (1.f / H_) - mu * mu;
  float rs = rsqrtf(var + LNEPS);
#pragma unroll
  for (int q = 0; q < 4; ++q) {
    s16x8 hi, lo;
#pragma unroll
    for (int i = 0; i < 8; ++i) {
      int col = c0 + q * 8 + i;
      float y = (f[q * 8 + i] - mu) * rs * lnw[col] + lnb[col];
      float h = tanh_fast(y);
      if (gdst) gdst[(size_t)r * H_ + col] = h;
      HiLo x = split1(h); hi[i] = x.hi; lo[i] = x.lo;
    }
    if (!gdst) { *(s16x8*)&dh[r][c0 + q * 8] = hi; *(s16x8*)&dl[r][c0 + q * 8] = lo; }
  }
}

#define MFMA(a, b, c) __builtin_amdgcn_mfma_f32_16x16x32_bf16(a, b, c, 0, 0, 0)
#define AF(buf, idx) (*(const s16x8*)&buf[lane & 15][(idx) + kb8])

__global__ __launch_bounds__(512, 1) void rnn_persist(
    const float* __restrict__ input, const float* __restrict__ hidden,
    const float* __restrict__ W_ih0, const float* __restrict__ W_hh0,
    const float* __restrict__ b_ih0, const float* __restrict__ b_hh0,
    const float* __restrict__ ln_w0, const float* __restrict__ ln_b0,
    const float* __restrict__ W_ih1, const float* __restrict__ W_hh1,
    const float* __restrict__ b_ih1, const float* __restrict__ b_hh1,
    const float* __restrict__ ln_w1, const float* __restrict__ ln_b1,
    float* gout, float* pre0,
    int* flag0, int* flag1, int* scnt1, float* stats1) {
  __shared__ ushort_t sAh[16][1032];
  __shared__ ushort_t sAl[16][1032];
  __shared__ float slnw[1024], slnb[1024];
  __shared__ float sacc[2][3][16][16];
  __shared__ float srstat[16][2];
  __shared__ float swst[2][16][2];

  const int tid = threadIdx.x;
  const int lane = tid & 63;
  const int w = tid >> 6;
  const int colt = w & 1, kh = w >> 1;  // 2 col-tiles x 4 K-quarters
  const int blk = blockIdx.x;
  const int layer = blk >> 7;
  const int id = blk & 127;
  const int rg = id >> 5, cg = id & 31;
  const int rowbase = rg * RB;
  const int cgl = cg * 32 + colt * 16 + (lane & 15);  // global output column
  const int kb8 = (lane >> 4) * 8;
  const int l15 = lane & 15;

  for (int i = tid; i < H_; i += 512) { slnw[i] = ln_w0[i]; slnb[i] = ln_b0[i]; }

  float bias = 0.f, w1v = 1.f, b1v = 0.f;

  if (layer == 0) {
    // ---- weights: x-quarter (K=128) + h-quarter (K=256), hi+lo ----
    s16x8 WhiX[4], WloX[4], WhiH[8], WloH[8];
#pragma unroll
    for (int s = 0; s < 4; ++s)
      ldw8s(W_ih0 + (size_t)cgl * IN_ + kh * 128 + s * 32 + kb8, WhiX[s], WloX[s]);
#pragma unroll
    for (int s = 0; s < 8; ++s)
      ldw8s(W_hh0 + (size_t)cgl * H_ + kh * 256 + s * 32 + kb8, WhiH[s], WloH[s]);
    if (kh == 0) bias = b_ih0[cgl] + b_hh0[cgl];
    __syncthreads();

    for (int t = 0; t < T_; ++t) {
      // x part first: independent of recurrence
      stageSplitX(input + ((size_t)t * B_ + rowbase) * IN_, sAh, sAl, tid);
      __syncthreads();
      f32x4 aP = (kh == 0) ? (f32x4){bias, bias, bias, bias} : (f32x4){0.f, 0.f, 0.f, 0.f};
      f32x4 aQ = {0.f, 0.f, 0.f, 0.f}, aR = {0.f, 0.f, 0.f, 0.f};
#pragma unroll
      for (int s = 0; s < 4; ++s) {
        s16x8 ah = AF(sAh, kh * 128 + s * 32), al = AF(sAl, kh * 128 + s * 32);
        aP = MFMA(ah, WhiX[s], aP); aQ = MFMA(ah, WloX[s], aQ); aR = MFMA(al, WhiX[s], aR);
      }
      if (tid == 0) {
        if (t > 0) spinN(&flag0[(t - 1) * 4 + rg], NCG);
        if (t >= RING) spinN(&flag1[(t - RING) * 4 + rg], NCG);
      }
      __syncthreads();  // also fences x-LDS reads before overwrite
      if (t == 0) stageSplitF32(hidden + (size_t)rowbase * H_, sAh, sAl, tid);
      else stageLTSplit(pre0 + ((size_t)((t - 1) & 7) * B_ + rowbase) * H_, sAh, sAl,
                        slnw, slnb, srstat, tid, nullptr);
      __syncthreads();
#pragma unroll
      for (int s = 0; s < 8; ++s) {
        s16x8 ah = AF(sAh, kh * 256 + s * 32), al = AF(sAl, kh * 256 + s * 32);
        aP = MFMA(ah, WhiH[s], aP); aQ = MFMA(ah, WloH[s], aQ); aR = MFMA(al, WhiH[s], aR);
      }
      f32x4 sum = aP + aQ + aR;
      if (kh > 0) {
#pragma unroll
        for (int j = 0; j < 4; ++j) sacc[colt][kh - 1][(lane >> 4) * 4 + j][l15] = sum[j];
      }
      __syncthreads();
      if (kh == 0) {
        float* dst = pre0 + ((size_t)(t & 7) * B_ + rowbase) * H_;
#pragma unroll
        for (int j = 0; j < 4; ++j) {
          int row = (lane >> 4) * 4 + j;
          float v = sum[j] + sacc[colt][0][row][l15] + sacc[colt][1][row][l15] +
                    sacc[colt][2][row][l15];
          dst[(size_t)row * H_ + cgl] = v;
        }
      }
      __threadfence();
      __syncthreads();
      if (tid == 0) addrel(&flag0[t * 4 + rg]);
    }
    // epilogue: h_fin[0] = tanh(LN0(pre0[T-1]))
    if (cg == 0) {
      if (tid == 0) spinN(&flag0[(T_ - 1) * 4 + rg], NCG);
      __syncthreads();
      stageLTSplit(pre0 + ((size_t)((T_ - 1) & 7) * B_ + rowbase) * H_, sAh, sAl,
                   slnw, slnb, srstat, tid,
                   gout + (size_t)T_ * B_ * H_ + (size_t)rowbase * H_);
    }
  } else {
    // ---- layer 1 weights: two h-quarters (K=256 each), hi+lo ----
    s16x8 WhiA[8], WloA[8], WhiB[8], WloB[8];
#pragma unroll
    for (int s = 0; s < 8; ++s)
      ldw8s(W_hh1 + (size_t)cgl * H_ + kh * 256 + s * 32 + kb8, WhiA[s], WloA[s]);
#pragma unroll
    for (int s = 0; s < 8; ++s)
      ldw8s(W_ih1 + (size_t)cgl * H_ + kh * 256 + s * 32 + kb8, WhiB[s], WloB[s]);
    if (kh == 0) { bias = b_ih1[cgl] + b_hh1[cgl]; w1v = ln_w1[cgl]; b1v = ln_b1[cgl]; }
    __syncthreads();

    for (int t = 0; t < T_; ++t) {
      if (tid == 0 && t > 0) spinN(&flag1[(t - 1) * 4 + rg], NCG);
      __syncthreads();
      if (t == 0) stageSplitF32(hidden + (size_t)B_ * H_ + (size_t)rowbase * H_, sAh, sAl, tid);
      else stageSplitF32(gout + ((size_t)(t - 1) * B_ + rowbase) * H_, sAh, sAl, tid);
      __syncthreads();
      f32x4 aP = (kh == 0) ? (f32x4){bias, bias, bias, bias} : (f32x4){0.f, 0.f, 0.f, 0.f};
      f32x4 aQ = {0.f, 0.f, 0.f, 0.f}, aR = {0.f, 0.f, 0.f, 0.f};
#pragma unroll
      for (int s = 0; s < 8; ++s) {
        s16x8 ah = AF(sAh, kh * 256 + s * 32), al = AF(sAl, kh * 256 + s * 32);
        aP = MFMA(ah, WhiA[s], aP); aQ = MFMA(ah, WloA[s], aQ); aR = MFMA(al, WhiA[s], aR);
      }
      if (tid == 0) spinN(&flag0[t * 4 + rg], NCG);
      __syncthreads();  // fences A-LDS reads before overwrite
      stageLTSplit(pre0 + ((size_t)(t & 7) * B_ + rowbase) * H_, sAh, sAl,
                   slnw, slnb, srstat, tid, nullptr);
      __syncthreads();
#pragma unroll
      for (int s = 0; s < 8; ++s) {
        s16x8 ah = AF(sAh, kh * 256 + s * 32), al = AF(sAl, kh * 256 + s * 32);
        aP = MFMA(ah, WhiB[s], aP); aQ = MFMA(ah, WloB[s], aQ); aR = MFMA(al, WhiB[s], aR);
      }
      f32x4 sum = aP + aQ + aR;
      if (kh > 0) {
#pragma unroll
        for (int j = 0; j < 4; ++j) sacc[colt][kh - 1][(lane >> 4) * 4 + j][l15] = sum[j];
      }
      __syncthreads();
      float pv[4];
      if (kh == 0) {
        float sj[4], qj[4];
#pragma unroll
        for (int j = 0; j < 4; ++j) {
          int row = (lane >> 4) * 4 + j;
          pv[j] = sum[j] + sacc[colt][0][row][l15] + sacc[colt][1][row][l15] +
                  sacc[colt][2][row][l15];
          sj[j] = pv[j]; qj[j] = pv[j] * pv[j];
        }
#pragma unroll
        for (int m = 1; m <= 8; m <<= 1) {
#pragma unroll
          for (int j = 0; j < 4; ++j) { sj[j] += __shfl_xor(sj[j], m, 64); qj[j] += __shfl_xor(qj[j], m, 64); }
        }
        if (l15 == 0) {
#pragma unroll
          for (int j = 0; j < 4; ++j) {
            swst[colt][(lane >> 4) * 4 + j][0] = sj[j];
            swst[colt][(lane >> 4) * 4 + j][1] = qj[j];
          }
        }
      }
      __syncthreads();
      if (tid < 16) {
        float s = swst[0][tid][0] + swst[1][tid][0];
        float q = swst[0][tid][1] + swst[1][tid][1];
        atomicAdd(&stats1[((size_t)t * 4 + rg) * 32 + tid * 2], s);
        atomicAdd(&stats1[((size_t)t * 4 + rg) * 32 + tid * 2 + 1], q);
      }
      __syncthreads();
      if (tid == 0) { addrel(&scnt1[t * 4 + rg]); spinN(&scnt1[t * 4 + rg], NCG); }
      __syncthreads();
      if (kh == 0) {
        const float* st = stats1 + ((size_t)t * 4 + rg) * 32;
        float* op = gout + ((size_t)t * B_ + rowbase) * H_;
#pragma unroll
        for (int j = 0; j < 4; ++j) {
          int row = (lane >> 4) * 4 + j;
          float mu = st[row * 2] * (1.f / H_);
          float var = st[row * 2 + 1] * (1.f / H_) - mu * mu;
          float rs = rsqrtf(var + LNEPS);
          float y = (pv[j] - mu) * rs * w1v + b1v;
          op[(size_t)row * H_ + cgl] = tanh_fast(y);
        }
      }
      __threadfence();
      __syncthreads();
      if (tid == 0) addrel(&flag1[t * 4 + rg]);
    }
    // epilogue: h_fin[1] = out[T-1]
    if (cg == 0) {
      if (tid == 0) spinN(&flag1[(T_ - 1) * 4 + rg], NCG);
      __syncthreads();
      int r = tid >> 5, c0 = (tid & 31) * 32;
      const float* src = gout + ((size_t)(T_ - 1) * B_ + rowbase + r) * H_ + c0;
      float* dst = gout + (size_t)T_ * B_ * H_ + (size_t)B_ * H_ + (size_t)(rowbase + r) * H_ + c0;
#pragma unroll
      for (int q = 0; q < 8; ++q) *(float4v*)(dst + q * 4) = *(const float4v*)(src + q * 4);
    }
  }
}

extern "C" void kernel_launch(void* const* d_in, const int* in_sizes, int n_in,
                              void* d_out, int out_size, void* d_ws, size_t ws_size,
                              hipStream_t stream) {
  const float* input = (const float*)d_in[0];
  const float* hidden = (const float*)d_in[1];
  const float* W_ih0 = (const float*)d_in[2];
  const float* W_hh0 = (const float*)d_in[3];
  const float* b_ih0 = (const float*)d_in[4];
  const float* b_hh0 = (const float*)d_in[5];
  const float* ln_w0 = (const float*)d_in[6];
  const float* ln_b0 = (const float*)d_in[7];
  const float* W_ih1 = (const float*)d_in[8];
  const float* W_hh1 = (const float*)d_in[9];
  const float* b_ih1 = (const float*)d_in[10];
  const float* b_hh1 = (const float*)d_in[11];
  const float* ln_w1 = (const float*)d_in[12];
  const float* ln_b1 = (const float*)d_in[13];
  float* gout = (float*)d_out;

  char* ws = (char*)d_ws;
  float* pre0 = (float*)ws;                             // 8*64*1024*4 = 2 MB
  char* ctrl = ws + (2u << 20);
  int* flag0 = (int*)ctrl;                              // 8 KB
  int* flag1 = (int*)(ctrl + 8192);                     // 8 KB
  int* scnt1 = (int*)(ctrl + 16384);                    // 8 KB
  float* stats1 = (float*)(ctrl + 24576);               // 512*4*32*4 = 256 KB

  (void)hipMemsetAsync(ctrl, 0, 24576 + 262144, stream);
  hipLaunchKernelGGL(rnn_persist, dim3(256), dim3(512), 0, stream,
                     input, hidden, W_ih0, W_hh0, b_ih0, b_hh0, ln_w0, ln_b0,
                     W_ih1, W_hh1, b_ih1, b_hh1, ln_w1, ln_b1,
                     gout, pre0, flag0, flag1, scnt1, stats1);
}